// Round 1
// baseline (585.077 us; speedup 1.0000x reference)
//
#include <hip/hip_runtime.h>

#define B_   64
#define N_   512
#define M_   512
#define Dm_  64
#define BIGF 1e30f
// gamma = 0.1
#define SINV 14.426950408889634f    // 1/(gamma*ln2)
#define GLN2 0.069314718055994531f  // gamma*ln2

// ---------------------------------------------------------------------------
// Kernel A: D[b,i,j] = sum_k (x[b,i,k]-y[b,j,k])^2, natural row-major layout.
// 64x64 tile per block, 256 threads, 4x4 micro-tile per thread (register
// tiling so LDS traffic is 128B/cell instead of 512B/cell).
// ---------------------------------------------------------------------------
__global__ __launch_bounds__(256) void dtw_dist_kernel(const float* __restrict__ x,
                                                       const float* __restrict__ y,
                                                       float* __restrict__ D) {
  __shared__ float xs[64][65];  // +1 pad: row stride 65 breaks bank aliasing
  __shared__ float ys[64][65];
  const int b  = blockIdx.z;
  const int i0 = blockIdx.y * 64;
  const int j0 = blockIdx.x * 64;
  const int tid = threadIdx.x;

  const float* xb = x + ((size_t)b * N_ + i0) * Dm_;
  const float* yb = y + ((size_t)b * M_ + j0) * Dm_;
#pragma unroll
  for (int r = 0; r < 16; ++r) {
    int idx = tid + r * 256;          // coalesced: 64 rows x 64 cols
    int row = idx >> 6, col = idx & 63;
    xs[row][col] = xb[idx];
    ys[row][col] = yb[idx];
  }
  __syncthreads();

  const int ty = tid >> 4, tx = tid & 15;
  float acc[4][4];
#pragma unroll
  for (int e = 0; e < 4; ++e)
#pragma unroll
    for (int f = 0; f < 4; ++f) acc[e][f] = 0.f;

#pragma unroll 8
  for (int k = 0; k < Dm_; ++k) {
    float xa[4], yv[4];
#pragma unroll
    for (int e = 0; e < 4; ++e) xa[e] = xs[ty * 4 + e][k];
#pragma unroll
    for (int f = 0; f < 4; ++f) yv[f] = ys[tx * 4 + f][k];
#pragma unroll
    for (int e = 0; e < 4; ++e)
#pragma unroll
      for (int f = 0; f < 4; ++f) {
        float t = xa[e] - yv[f];
        acc[e][f] = fmaf(t, t, acc[e][f]);
      }
  }

  float* Db = D + ((size_t)b * N_ + i0) * M_ + j0;
#pragma unroll
  for (int e = 0; e < 4; ++e) {
    float4 v4 = make_float4(acc[e][0], acc[e][1], acc[e][2], acc[e][3]);
    *(float4*)(Db + (size_t)(ty * 4 + e) * M_ + tx * 4) = v4;  // coalesced 16B
  }
}

// ---------------------------------------------------------------------------
// Kernel B: soft-DTW anti-diagonal DP, one workgroup (512 threads) per batch.
// Thread t owns DP row i = t+1. Three rotating diagonals in LDS, one barrier
// per step. FUSED=true computes the distance on the fly (no workspace).
// After the DP, the same block writes out[b] = x[b] * exp(-dist).
// ---------------------------------------------------------------------------
template <bool FUSED>
__global__ __launch_bounds__(512) void dtw_dp_kernel(const float* __restrict__ x,
                                                     const float* __restrict__ y,
                                                     const float* __restrict__ D,
                                                     float* __restrict__ out) {
  __shared__ float v[3][516];
  const int b = blockIdx.x;
  const int t = threadIdx.x;  // 0..511
  const int i = t + 1;        // DP row index 1..512

  // init: diag p=0 -> buffer 0 (R[0,0]=0, rest BIG); diag p=1 -> buffer 1 (all BIG)
  if (t == 0) { v[0][0] = 0.f; v[1][0] = BIGF; v[2][0] = BIGF; }
  v[0][i] = BIGF;
  v[1][i] = BIGF;

  const float* Drow = FUSED ? nullptr : (D + ((size_t)b * N_ + t) * M_);

  float xr[Dm_];
  if (FUSED) {
    const float* xrow = x + ((size_t)b * N_ + t) * Dm_;  // row i-1 = t
#pragma unroll
    for (int k = 0; k < Dm_; ++k) xr[k] = xrow[k];
  }
  __syncthreads();

  int cur = 2, m1 = 1, m2 = 0;  // cur = p%3 at step p
  float dcur = 0.f;
  if (!FUSED) {
    if (i == 1) dcur = Drow[0];  // d for p=2 (only i=1 is valid there)
  }

  for (int p = 2; p <= N_ + M_; ++p) {
    const int j = p - i;
    const bool valid = (j >= 1) && (j <= M_);

    // prefetch next step's d (hides L1/L2 latency under compute+barrier)
    float dnext = 0.f;
    if (!FUSED) {
      const int jn = j + 1;
      if (jn >= 1 && jn <= M_) dnext = Drow[jn - 1];
    }

    float d;
    if (FUSED) {
      d = 0.f;
      if (valid) {
        const float* yr = y + ((size_t)b * M_ + (j - 1)) * Dm_;
        float a = 0.f;
#pragma unroll
        for (int k = 0; k < Dm_; ++k) {
          float u = xr[k] - yr[k];
          a = fmaf(u, u, a);
        }
        d = a;
      }
    } else {
      d = dcur;
    }

    // softmin(R[i-1,j], R[i,j-1], R[i-1,j-1]); reads hit buffers m1/m2, write
    // goes to cur (holds dead diag p-3), so no intra-step race.
    const float a  = v[m1][i - 1];
    const float bb = v[m1][i];
    const float c  = v[m2][i - 1];
    const float mn = fminf(fminf(a, bb), c);
    const float s = exp2f((mn - a) * SINV) + exp2f((mn - bb) * SINV) +
                    exp2f((mn - c) * SINV);
    const float r = valid ? (d + mn - GLN2 * log2f(s)) : BIGF;

    v[cur][i] = r;
    if (t == 0) v[cur][0] = BIGF;  // R[0,p] = BIG (buffer reuse would leak R[0,0]=0)
    __syncthreads();

    dcur = dnext;
    const int tmp = m2; m2 = m1; m1 = cur; cur = tmp;
  }

  // diag N+M lives in buffer (N+M)%3; dist = R[N,M]
  const float dist = v[(N_ + M_) % 3][N_];
  const float w = expf(-dist);

  const float* xb = x + (size_t)b * N_ * Dm_;
  float* ob = out + (size_t)b * N_ * Dm_;
#pragma unroll
  for (int e = 0; e < (N_ * Dm_) / 512; ++e) {
    const int idx = e * 512 + t;  // coalesced
    ob[idx] = xb[idx] * w;
  }
}

// ---------------------------------------------------------------------------
extern "C" void kernel_launch(void* const* d_in, const int* in_sizes, int n_in,
                              void* d_out, int out_size, void* d_ws, size_t ws_size,
                              hipStream_t stream) {
  const float* x = (const float*)d_in[0];
  const float* y = (const float*)d_in[1];
  float* out = (float*)d_out;

  const size_t need = (size_t)B_ * N_ * M_ * sizeof(float);  // 64 MiB
  if (ws_size >= need) {
    float* Dbuf = (float*)d_ws;
    dim3 g(M_ / 64, N_ / 64, B_);
    dtw_dist_kernel<<<g, dim3(256), 0, stream>>>(x, y, Dbuf);
    dtw_dp_kernel<false><<<dim3(B_), dim3(512), 0, stream>>>(x, y, Dbuf, out);
  } else {
    dtw_dp_kernel<true><<<dim3(B_), dim3(512), 0, stream>>>(x, y, nullptr, out);
  }
}

// Round 2
// 354.608 us; speedup vs baseline: 1.6499x; 1.6499x over previous
//
#include <hip/hip_runtime.h>

#define B_   64
#define N_   512
#define M_   512
#define Dm_  64
#define BIGF 1e30f
// gamma = 0.1; work in scaled units R' = R / (gamma*ln2) so softmin is
// r' = d' + mn' - log2( 2^(mn'-a') + 2^(mn'-b') + 2^(mn'-c') ), no muls.
#define SINV 14.426950408889634f    // 1/(gamma*ln2)
#define LAG  8                      // inter-wave column lag (= barrier period)

// ---------------------------------------------------------------------------
// Kernel A: D'[b,i,j] = SINV * sum_k (x[b,i,k]-y[b,j,k])^2  (pre-scaled).
// 128x128 tile, 256 threads, 8x8 micro-tile: 64 FMA per 16 LDS reads.
// ---------------------------------------------------------------------------
__global__ __launch_bounds__(256) void dtw_dist_kernel(const float* __restrict__ x,
                                                       const float* __restrict__ y,
                                                       float* __restrict__ D) {
  __shared__ float xs[128][65];   // stride 65: xa reads broadcast, ys 4-way max
  __shared__ float ys[128][65];
  const int b  = blockIdx.z;
  const int i0 = blockIdx.y * 128;
  const int j0 = blockIdx.x * 128;
  const int tid = threadIdx.x;

  const float* xb = x + ((size_t)b * N_ + i0) * Dm_;
  const float* yb = y + ((size_t)b * M_ + j0) * Dm_;
#pragma unroll
  for (int r = 0; r < 8; ++r) {
    int v4 = tid + r * 256;               // float4 index over 128x64 tile
    int row = v4 >> 4, c4 = (v4 & 15) * 4;
    float4 xv = *(const float4*)(xb + (size_t)row * Dm_ + c4);
    float4 yv = *(const float4*)(yb + (size_t)row * Dm_ + c4);
    xs[row][c4 + 0] = xv.x; xs[row][c4 + 1] = xv.y;
    xs[row][c4 + 2] = xv.z; xs[row][c4 + 3] = xv.w;
    ys[row][c4 + 0] = yv.x; ys[row][c4 + 1] = yv.y;
    ys[row][c4 + 2] = yv.z; ys[row][c4 + 3] = yv.w;
  }
  __syncthreads();

  const int ty = tid >> 4, tx = tid & 15;
  float acc[8][8];
#pragma unroll
  for (int e = 0; e < 8; ++e)
#pragma unroll
    for (int f = 0; f < 8; ++f) acc[e][f] = 0.f;

#pragma unroll 4
  for (int k = 0; k < Dm_; ++k) {
    float xa[8], yv[8];
#pragma unroll
    for (int e = 0; e < 8; ++e) xa[e] = xs[ty * 8 + e][k];
#pragma unroll
    for (int f = 0; f < 8; ++f) yv[f] = ys[tx * 8 + f][k];
#pragma unroll
    for (int e = 0; e < 8; ++e)
#pragma unroll
      for (int f = 0; f < 8; ++f) {
        float t = xa[e] - yv[f];
        acc[e][f] = fmaf(t, t, acc[e][f]);
      }
  }

  float* Db = D + ((size_t)b * N_ + i0) * M_ + j0;
#pragma unroll
  for (int e = 0; e < 8; ++e) {
    const int row = ty * 8 + e;
#pragma unroll
    for (int f4 = 0; f4 < 2; ++f4) {
      float4 v4 = make_float4(acc[e][f4 * 4 + 0] * SINV, acc[e][f4 * 4 + 1] * SINV,
                              acc[e][f4 * 4 + 2] * SINV, acc[e][f4 * 4 + 3] * SINV);
      *(float4*)(Db + (size_t)row * M_ + tx * 8 + f4 * 4) = v4;
    }
  }
}

// ---------------------------------------------------------------------------
// Kernel B: skewed-pipeline soft-DTW DP. One block (512 thr = 8 waves) per
// batch. Lane t owns row i=t+1, sweeps columns; global step s computes the
// cell at column j = s - skew(t) + 1, skew(t) = t + 8*wave.
//   a = R'[i-1][j]   : neighbor's value from step s-1  -> __shfl_up(r,1)
//   b = R'[i][j-1]   : own value from previous active step (register)
//   c = R'[i-1][j-1] : neighbor's value from step s-2  -> saved prev shuffle
// Wave boundaries: 16-slot LDS ring per boundary, lag 8 => consumer reads
// values >=9 steps old, all published before the previous barrier; barrier
// only every 8 steps. D row per lane streamed with 8-step register prefetch.
// ---------------------------------------------------------------------------
__global__ __launch_bounds__(512) void dtw_dp_kernel(const float* __restrict__ Dmat,
                                                     const float* __restrict__ x,
                                                     float* __restrict__ out) {
  const int b    = blockIdx.x;
  const int t    = threadIdx.x;   // 0..511
  const int w    = t >> 6;        // wave 0..7
  const int lane = t & 63;
  const int skew = t + w * LAG;   // max 511 + 56 = 567

  __shared__ float ring[7][16];
  __shared__ float bcast;

  if (t < 7 * 16) ((float*)ring)[t] = BIGF;
  __syncthreads();

  const float* Drow = Dmat + ((size_t)b * N_ + t) * M_;   // lane's D' row
  const float* rbase = ring[w > 0 ? w - 1 : 0];

  float A = (t == 0) ? 0.0f : BIGF;  // becomes c at first active step (R'[0][0]=0)
  float B = BIGF;                    // R'[i][0] = BIG
  float r = BIGF;                    // last computed value (shfl source)

  float dcur[8], dnxt[8];
#pragma unroll
  for (int k = 0; k < 8; ++k) {
    int idx = k - skew; idx = idx < 0 ? 0 : idx;
    dcur[k] = Drow[idx];
  }

  const int NBLK = (512 + 511 + 7 * LAG + 1 + 7) / 8;   // 135 -> 1080 steps
  for (int blk = 0; blk < NBLK; ++blk) {
    const int s0 = blk * 8;

    // prefetch next block's d' (clamped; garbage values are masked by `active`)
#pragma unroll
    for (int k = 0; k < 8; ++k) {
      int idx = s0 + 8 + k - skew;
      idx = idx < 0 ? 0 : (idx > M_ - 1 ? M_ - 1 : idx);
      dnxt[k] = Drow[idx];
    }

    // ring values for this block: slot (s-9) mod 16 == (s+7) & 15.
    // Same address across the wave -> LDS broadcast, cheap.
    float rv[8];
#pragma unroll
    for (int k = 0; k < 8; ++k)
      rv[k] = (w > 0) ? rbase[(s0 + k + 7) & 15] : BIGF;

#pragma unroll
    for (int k = 0; k < 8; ++k) {
      const int s = s0 + k;
      float nb = __shfl_up(r, 1);
      if (lane == 0) nb = rv[k];          // wave 0: BIGF; waves 1-7: ring
      const float C = A;                  // neighbor @ s-2 = R'[i-1][j-1]
      A = nb;                             // neighbor @ s-1 = R'[i-1][j]
      const int n = s - skew;
      const bool active = (n >= 0) && (n < M_);
      const float mn = fminf(fminf(A, B), C);
      const float e  = exp2f(mn - A) + exp2f(mn - B) + exp2f(mn - C);
      const float rr = dcur[k] + mn - log2f(e);
      r = active ? rr : BIGF;
      if (active) B = rr;
      if (lane == 63 && w < 7) ring[w][s & 15] = r;   // publish boundary row
    }
#pragma unroll
    for (int k = 0; k < 8; ++k) dcur[k] = dnxt[k];

    __syncthreads();   // every 8 steps; dnxt loads had ~8 steps to land
  }

  if (t == N_ - 1) bcast = B;            // R'[512][512]
  __syncthreads();
  const float wsc = exp2f(-0.1f * bcast); // w = exp(-R) = 2^(-gamma * R')

  const float4* x4 = (const float4*)(x + (size_t)b * N_ * Dm_);
  float4* o4 = (float4*)(out + (size_t)b * N_ * Dm_);
#pragma unroll
  for (int e = 0; e < (N_ * Dm_ / 4) / 512; ++e) {
    float4 v = x4[e * 512 + t];
    v.x *= wsc; v.y *= wsc; v.z *= wsc; v.w *= wsc;
    o4[e * 512 + t] = v;
  }
}

// ---------------------------------------------------------------------------
// Fallback (no workspace): original barrier-per-step fused DP. Slow but correct.
// ---------------------------------------------------------------------------
__global__ __launch_bounds__(512) void dtw_dp_fused(const float* __restrict__ x,
                                                    const float* __restrict__ y,
                                                    float* __restrict__ out) {
  __shared__ float v[3][516];
  const int b = blockIdx.x;
  const int t = threadIdx.x;
  const int i = t + 1;
  if (t == 0) { v[0][0] = 0.f; v[1][0] = BIGF; v[2][0] = BIGF; }
  v[0][i] = BIGF;
  v[1][i] = BIGF;
  float xr[Dm_];
  const float* xrow = x + ((size_t)b * N_ + t) * Dm_;
#pragma unroll
  for (int k = 0; k < Dm_; ++k) xr[k] = xrow[k];
  __syncthreads();
  int cur = 2, m1 = 1, m2 = 0;
  const float GLN2 = 0.069314718055994531f;
  for (int p = 2; p <= N_ + M_; ++p) {
    const int j = p - i;
    const bool valid = (j >= 1) && (j <= M_);
    float d = 0.f;
    if (valid) {
      const float* yr = y + ((size_t)b * M_ + (j - 1)) * Dm_;
      float a = 0.f;
#pragma unroll
      for (int k = 0; k < Dm_; ++k) { float u = xr[k] - yr[k]; a = fmaf(u, u, a); }
      d = a;
    }
    const float a  = v[m1][i - 1];
    const float bb = v[m1][i];
    const float c  = v[m2][i - 1];
    const float mn = fminf(fminf(a, bb), c);
    const float s = exp2f((mn - a) * SINV) + exp2f((mn - bb) * SINV) +
                    exp2f((mn - c) * SINV);
    const float rr = valid ? (d + mn - GLN2 * log2f(s)) : BIGF;
    v[cur][i] = rr;
    if (t == 0) v[cur][0] = BIGF;
    __syncthreads();
    const int tmp = m2; m2 = m1; m1 = cur; cur = tmp;
  }
  const float dist = v[(N_ + M_) % 3][N_];
  const float wsc = expf(-dist);
  const float* xb = x + (size_t)b * N_ * Dm_;
  float* ob = out + (size_t)b * N_ * Dm_;
#pragma unroll
  for (int e = 0; e < (N_ * Dm_) / 512; ++e) {
    const int idx = e * 512 + t;
    ob[idx] = xb[idx] * wsc;
  }
}

// ---------------------------------------------------------------------------
extern "C" void kernel_launch(void* const* d_in, const int* in_sizes, int n_in,
                              void* d_out, int out_size, void* d_ws, size_t ws_size,
                              hipStream_t stream) {
  const float* x = (const float*)d_in[0];
  const float* y = (const float*)d_in[1];
  float* out = (float*)d_out;

  const size_t need = (size_t)B_ * N_ * M_ * sizeof(float);  // 64 MiB
  if (ws_size >= need) {
    float* Dbuf = (float*)d_ws;
    dim3 g(M_ / 128, N_ / 128, B_);
    dtw_dist_kernel<<<g, dim3(256), 0, stream>>>(x, y, Dbuf);
    dtw_dp_kernel<<<dim3(B_), dim3(512), 0, stream>>>(Dbuf, x, out);
  } else {
    dtw_dp_fused<<<dim3(B_), dim3(512), 0, stream>>>(x, y, out);
  }
}